// Round 1
// baseline (435.999 us; speedup 1.0000x reference)
//
#include <hip/hip_runtime.h>
#include <math.h>

// SpiralNet: 3 layers of gather(12 rows) + dense + (ELU on first two).
// Layer l: out[i,j] = b[j] + sum_{s<12, c<CIN} h[idx[i,s], c] * W[(s*CIN+c)*COUT + j]
// fp32 baseline: block computes BM x COUT tile, thread computes 4x4 register tile.

template<int CIN, int COUT, bool ELU>
__global__ __launch_bounds__(256)
void spiral_layer(const float* __restrict__ h,
                  const int* __restrict__ idx,
                  const float* __restrict__ W,
                  const float* __restrict__ bias,
                  float* __restrict__ out, int n)
{
    constexpr int TXG = COUT / 4;    // column groups (threads along N-dim of tile)
    constexpr int TYG = 256 / TXG;   // row groups
    constexpr int BM  = TYG * 4;     // rows per block (64 for COUT=64, 128 for COUT=32)
    constexpr int APITCH = CIN + 4;  // +4 floats keeps b128 reads 16B-aligned, banks ~2-way

    __shared__ alignas(16) float As[BM * APITCH];
    __shared__ alignas(16) float Ws[CIN * COUT];
    __shared__ int lidx[BM * 12];

    const int tid = threadIdx.x;
    const int tx  = tid % TXG;       // col group: cols tx*4 .. tx*4+3
    const int ty  = tid / TXG;       // row group: rows ty*4 .. ty*4+3
    const int i0  = blockIdx.x * BM;

    // Stage gather indices for this block's rows (clamped for tail).
    for (int j = tid; j < BM * 12; j += 256) {
        const int r = j / 12;
        const int i = i0 + r;
        lidx[j] = (i < n) ? idx[i * 12 + (j % 12)] : 0;
    }

    float acc[4][4];
    #pragma unroll
    for (int u = 0; u < 4; ++u)
        #pragma unroll
        for (int v = 0; v < 4; ++v)
            acc[u][v] = 0.0f;

    #pragma unroll 1
    for (int s = 0; s < 12; ++s) {
        __syncthreads();  // protects lidx on s=0, As/Ws reuse on s>0

        // Stage gathered A chunk: As[r][c] = h[lidx[r,s]][c]
        constexpr int AV = BM * CIN / 4;
        for (int j = tid; j < AV; j += 256) {
            const int r = j / (CIN / 4);
            const int c = j % (CIN / 4);
            const int row = lidx[r * 12 + s];
            const float4 v = *reinterpret_cast<const float4*>(&h[(size_t)row * CIN + c * 4]);
            *reinterpret_cast<float4*>(&As[r * APITCH + c * 4]) = v;
        }
        // Stage W chunk (contiguous CIN*COUT floats for step s).
        constexpr int WV = CIN * COUT / 4;
        const float* Wc = W + (size_t)s * CIN * COUT;
        for (int j = tid; j < WV; j += 256) {
            *reinterpret_cast<float4*>(&Ws[j * 4]) =
                *reinterpret_cast<const float4*>(&Wc[j * 4]);
        }
        __syncthreads();

        #pragma unroll 2
        for (int kk = 0; kk < CIN; kk += 4) {
            float a[4][4], b[4][4];
            #pragma unroll
            for (int u = 0; u < 4; ++u) {
                const float4 t = *reinterpret_cast<const float4*>(
                    &As[(ty * 4 + u) * APITCH + kk]);
                a[u][0] = t.x; a[u][1] = t.y; a[u][2] = t.z; a[u][3] = t.w;
            }
            #pragma unroll
            for (int q = 0; q < 4; ++q) {
                const float4 t = *reinterpret_cast<const float4*>(
                    &Ws[(kk + q) * COUT + tx * 4]);
                b[q][0] = t.x; b[q][1] = t.y; b[q][2] = t.z; b[q][3] = t.w;
            }
            #pragma unroll
            for (int u = 0; u < 4; ++u)
                #pragma unroll
                for (int q = 0; q < 4; ++q)
                    #pragma unroll
                    for (int v = 0; v < 4; ++v)
                        acc[u][v] = fmaf(a[u][q], b[q][v], acc[u][v]);
        }
    }

    // Epilogue: bias + optional ELU, float4 store.
    float bv[4];
    #pragma unroll
    for (int v = 0; v < 4; ++v) bv[v] = bias[tx * 4 + v];

    #pragma unroll
    for (int u = 0; u < 4; ++u) {
        const int i = i0 + ty * 4 + u;
        if (i < n) {
            float o[4];
            #pragma unroll
            for (int v = 0; v < 4; ++v) {
                float t = acc[u][v] + bv[v];
                if (ELU) t = (t > 0.0f) ? t : (__expf(t) - 1.0f);
                o[v] = t;
            }
            float4 st;
            st.x = o[0]; st.y = o[1]; st.z = o[2]; st.w = o[3];
            *reinterpret_cast<float4*>(&out[(size_t)i * COUT + tx * 4]) = st;
        }
    }
}

extern "C" void kernel_launch(void* const* d_in, const int* in_sizes, int n_in,
                              void* d_out, int out_size, void* d_ws, size_t ws_size,
                              hipStream_t stream) {
    const float* x   = (const float*)d_in[0];   // [N,32,1] fp32 (contiguous [N,32])
    const int*   idx = (const int*)d_in[1];     // [N,12] int32
    const float* W0  = (const float*)d_in[2];   // [384,64]
    const float* b0  = (const float*)d_in[3];   // [64]
    const float* W1  = (const float*)d_in[4];   // [768,64]
    const float* b1  = (const float*)d_in[5];   // [64]
    const float* W2  = (const float*)d_in[6];   // [768,32]
    const float* b2  = (const float*)d_in[7];   // [32]
    float* out = (float*)d_out;                 // [N,32,1] fp32

    const int n = in_sizes[0] / 32;             // N = 100000

    float* h1 = (float*)d_ws;                   // [N,64] fp32 (25.6 MB)
    float* h2 = h1 + (size_t)n * 64;            // [N,64] fp32 (25.6 MB)

    dim3 blk(256);
    spiral_layer<32, 64, true ><<<(n + 63)  / 64,  blk, 0, stream>>>(x,  idx, W0, b0, h1,  n);
    spiral_layer<64, 64, true ><<<(n + 63)  / 64,  blk, 0, stream>>>(h1, idx, W1, b1, h2,  n);
    spiral_layer<64, 32, false><<<(n + 127) / 128, blk, 0, stream>>>(h2, idx, W2, b2, out, n);
}

// Round 2
// 215.974 us; speedup vs baseline: 2.0188x; 2.0188x over previous
//
#include <hip/hip_runtime.h>
#include <math.h>

// SpiralNet bf16-MFMA version.
// Layer: out[i,j] = b[j] + sum_{k<12*CIN} A[i,k] * W[k,j],  A[i, s*CIN+c] = h[idx[i,s], c]
// - A-fragments gathered DIRECTLY from global into mfma_f32_16x16x32_bf16 layout
//   (lane m=lane&15 row, quad=lane>>4 picks k-octet) -- no LDS, no barriers.
// - W pre-transposed+converted to bf16 WT[COUT][K] so B-frags are contiguous 16B loads.
// - h1/h2 intermediates stored bf16 (same rounding point as converting at load).
// - MR=4 row-tiles per wave amortizes B-frag loads 4x.

typedef __bf16 bf16;
typedef bf16  bf16x8 __attribute__((ext_vector_type(8)));
typedef float f32x4  __attribute__((ext_vector_type(4)));

// W [K][COUT] f32  ->  WT [COUT][K] bf16
__global__ __launch_bounds__(256)
void prep_wt(const float* __restrict__ W, bf16* __restrict__ WT, int K, int COUT) {
    int e = blockIdx.x * 256 + threadIdx.x;
    if (e < K * COUT) {
        int k = e / COUT, j = e % COUT;
        WT[j * K + k] = (bf16)W[e];
    }
}

template<int CIN, int COUT, bool ELU, typename TIN, typename TOUT>
__global__ __launch_bounds__(256)
void spiral_mfma(const TIN* __restrict__ h, const int* __restrict__ idx,
                 const bf16* __restrict__ WT, const float* __restrict__ bias,
                 TOUT* __restrict__ out, int n)
{
    constexpr int K  = 12 * CIN;
    constexpr int NT = COUT / 16;   // 16-col B tiles
    constexpr int MR = 4;           // 16-row A tiles per wave

    const int wave = threadIdx.x >> 6;
    const int lane = threadIdx.x & 63;
    const int m    = lane & 15;     // A row within tile / B col within tile
    const int quad = lane >> 4;     // picks k-octet
    const int i0   = (blockIdx.x * 4 + wave) * (16 * MR);
    if (i0 >= n) return;

    f32x4 acc[MR][NT] = {};

    int ir[MR];
    #pragma unroll
    for (int rt = 0; rt < MR; ++rt) {
        int i = i0 + rt * 16 + m;
        ir[rt] = (i < n) ? i : (n - 1);
    }

    #pragma unroll 1
    for (int s = 0; s < 12; ++s) {
        int rg[MR];
        #pragma unroll
        for (int rt = 0; rt < MR; ++rt) rg[rt] = idx[ir[rt] * 12 + s];

        #pragma unroll
        for (int c0 = 0; c0 < CIN; c0 += 32) {
            const int kbase = s * CIN + c0 + quad * 8;

            bf16x8 b[NT];
            #pragma unroll
            for (int t = 0; t < NT; ++t)
                b[t] = *reinterpret_cast<const bf16x8*>(WT + (size_t)(t * 16 + m) * K + kbase);

            #pragma unroll
            for (int rt = 0; rt < MR; ++rt) {
                bf16x8 a;
                const TIN* hrow = h + (size_t)rg[rt] * CIN + c0 + quad * 8;
                if constexpr (sizeof(TIN) == 2) {
                    a = *reinterpret_cast<const bf16x8*>(hrow);
                } else {
                    const f32x4* p = reinterpret_cast<const f32x4*>(hrow);
                    f32x4 f0 = p[0], f1 = p[1];
                    a = (bf16x8){(bf16)f0[0], (bf16)f0[1], (bf16)f0[2], (bf16)f0[3],
                                 (bf16)f1[0], (bf16)f1[1], (bf16)f1[2], (bf16)f1[3]};
                }
                #pragma unroll
                for (int t = 0; t < NT; ++t)
                    acc[rt][t] = __builtin_amdgcn_mfma_f32_16x16x32_bf16(a, b[t], acc[rt][t], 0, 0, 0);
            }
        }
    }

    // Epilogue: D[row = quad*4+g][col = t*16+m]
    #pragma unroll
    for (int t = 0; t < NT; ++t) {
        const int col = t * 16 + m;
        const float bv = bias[col];
        #pragma unroll
        for (int rt = 0; rt < MR; ++rt) {
            if (i0 + rt * 16 < n) {   // n%16==0 -> whole 16-row tile valid or not
                #pragma unroll
                for (int g = 0; g < 4; ++g) {
                    const int row = i0 + rt * 16 + quad * 4 + g;
                    float v = acc[rt][t][g] + bv;
                    if (ELU) v = (v > 0.f) ? v : (__expf(v) - 1.f);
                    out[(size_t)row * COUT + col] = (TOUT)v;
                }
            }
        }
    }
}

extern "C" void kernel_launch(void* const* d_in, const int* in_sizes, int n_in,
                              void* d_out, int out_size, void* d_ws, size_t ws_size,
                              hipStream_t stream) {
    const float* x   = (const float*)d_in[0];   // [N,32] fp32
    const int*   idx = (const int*)d_in[1];     // [N,12]
    const float* W0  = (const float*)d_in[2];   // [384,64]
    const float* b0  = (const float*)d_in[3];
    const float* W1  = (const float*)d_in[4];   // [768,64]
    const float* b1  = (const float*)d_in[5];
    const float* W2  = (const float*)d_in[6];   // [768,32]
    const float* b2  = (const float*)d_in[7];
    float* out = (float*)d_out;                 // [N,32] fp32

    const int n = in_sizes[0] / 32;             // N = 100000

    // workspace layout (bf16 elements, all 16B-aligned)
    bf16* h1  = (bf16*)d_ws;                    // [n,64]  12.8 MB
    bf16* h2  = h1 + (size_t)n * 64;            // [n,64]  12.8 MB
    bf16* WT0 = h2 + (size_t)n * 64;            // [64,384]
    bf16* WT1 = WT0 + 64 * 384;                 // [64,768]
    bf16* WT2 = WT1 + 64 * 768;                 // [32,768]

    dim3 blk(256);
    prep_wt<<<(384 * 64 + 255) / 256, blk, 0, stream>>>(W0, WT0, 384, 64);
    prep_wt<<<(768 * 64 + 255) / 256, blk, 0, stream>>>(W1, WT1, 768, 64);
    prep_wt<<<(768 * 32 + 255) / 256, blk, 0, stream>>>(W2, WT2, 768, 32);

    // each block: 4 waves x 64 rows = 256 rows
    const int rows_per_block = 256;
    const int grid = (n + rows_per_block - 1) / rows_per_block;
    spiral_mfma<32, 64, true,  float, bf16 ><<<grid, blk, 0, stream>>>(x,  idx, WT0, b0, h1,  n);
    spiral_mfma<64, 64, true,  bf16,  bf16 ><<<grid, blk, 0, stream>>>(h1, idx, WT1, b1, h2,  n);
    spiral_mfma<64, 32, false, bf16,  float><<<grid, blk, 0, stream>>>(h2, idx, WT2, b2, out, n);
}